// Round 2
// 580.970 us; speedup vs baseline: 1.0118x; 1.0118x over previous
//
#include <hip/hip_runtime.h>

// RSWAF: out[..., g] = 1 - tanh((x - grid[g]) * inv_den)^2
//      = sech^2(y) = 4u / (1+u)^2,  u = exp(-2|y|)   (exact rewrite, no overflow)
//
// Memory-bound: 512 MiB out (write-once) + 64 MiB in (read-once).
// Grid-stride persistent launch (2048 blocks x 256 = 32 waves/CU at tiny VGPR
// count) to amortize block turnover; nontemporal loads/stores keep the
// streaming data out of L2/LLC. Each thread iteration -> one float4 of output
// (4 consecutive grid values), perfectly coalesced 16 B/lane stores.

// Native clang vector type: required by __builtin_nontemporal_store
// (HIP's float4 is a class and is rejected by the builtin).
typedef float v4f __attribute__((ext_vector_type(4)));

__global__ __launch_bounds__(256) void rswaf_kernel(
    const float* __restrict__ x,
    const float* __restrict__ grid,   // 8 floats
    const float* __restrict__ inv_den_p,
    v4f* __restrict__ out,
    int n4)                           // number of float4 outputs
{
    // c = 2 * log2(e) * |inv_den|  (uniform; scalar path)
    const float c = fabsf(inv_den_p[0]) * 2.8853900817779268f;

    // Both halves of the 8-entry grid, hoisted out of the loop.
    const v4f g0 = ((const v4f*)grid)[0];
    const v4f g1 = ((const v4f*)grid)[1];

    const int stride = gridDim.x * blockDim.x;
    for (int j = blockIdx.x * blockDim.x + threadIdx.x; j < n4; j += stride) {
        // out elements [4*j, 4*j+4): x index = j>>1, grid half = j&1.
        // Per wave: 64 lanes hit 32 consecutive x dwords (128 B segment,
        // broadcast to lane pairs) -> coalesced; store is 1 KiB contiguous.
        const float xi = __builtin_nontemporal_load(&x[j >> 1]);
        const v4f g = (j & 1) ? g1 : g0;

        float d0 = fabsf(xi - g.x);
        float d1 = fabsf(xi - g.y);
        float d2 = fabsf(xi - g.z);
        float d3 = fabsf(xi - g.w);
        float u0 = __builtin_amdgcn_exp2f(-c * d0);
        float u1 = __builtin_amdgcn_exp2f(-c * d1);
        float u2 = __builtin_amdgcn_exp2f(-c * d2);
        float u3 = __builtin_amdgcn_exp2f(-c * d3);
        float t0 = 1.0f + u0, t1 = 1.0f + u1, t2 = 1.0f + u2, t3 = 1.0f + u3;
        v4f r;
        r.x = 4.0f * u0 * __builtin_amdgcn_rcpf(t0 * t0);
        r.y = 4.0f * u1 * __builtin_amdgcn_rcpf(t1 * t1);
        r.z = 4.0f * u2 * __builtin_amdgcn_rcpf(t2 * t2);
        r.w = 4.0f * u3 * __builtin_amdgcn_rcpf(t3 * t3);

        __builtin_nontemporal_store(r, &out[j]);
    }
}

extern "C" void kernel_launch(void* const* d_in, const int* in_sizes, int n_in,
                              void* d_out, int out_size, void* d_ws, size_t ws_size,
                              hipStream_t stream) {
    const float* x       = (const float*)d_in[0];   // 16*64*128*128 fp32
    const float* grid    = (const float*)d_in[1];   // 8 fp32
    const float* inv_den = (const float*)d_in[2];   // 1 fp32
    float* out = (float*)d_out;

    const int n4 = out_size / 4;                    // float4 outputs
    const int block = 256;
    int nblocks = (n4 + block - 1) / block;
    if (nblocks > 2048) nblocks = 2048;             // grid-stride the rest
    rswaf_kernel<<<nblocks, block, 0, stream>>>(x, grid, inv_den,
                                                (v4f*)out, n4);
}

// Round 3
// 578.087 us; speedup vs baseline: 1.0168x; 1.0050x over previous
//
#include <hip/hip_runtime.h>

// RSWAF: out[..., g] = 1 - tanh((x - grid[g]) * inv_den)^2 = sech^2(y)
//      = 4u / (1+u)^2,  u = exp(-2y)   (symmetric under u -> 1/u, so no abs
//        needed; exponent clamped to +-100 so u stays finite and the
//        expression degrades gracefully to 0 at the tails)
//
// Memory-bound: 512 MiB out (write-once) + 64 MiB in (read-once).
// This revision attacks latency/ILP: 4x unrolled grid-stride loop with all 4
// x-loads issued up front (4x memory-level parallelism), and an exp2-chain
// rewrite u_k = u_0 * p_k (p_k uniform constants) that cuts transcendentals
// from 8 exp2/x to 1 exp2/iteration.

typedef float v4f __attribute__((ext_vector_type(4)));

__global__ __launch_bounds__(256) void rswaf_kernel(
    const float* __restrict__ x,
    const float* __restrict__ grid,   // 8 floats
    const float* __restrict__ inv_den_p,
    v4f* __restrict__ out,
    int n4)                           // number of float4 outputs
{
    // C = 2 * log2(e) * |inv_den|  ->  u = exp(-2y) = exp2(-C*(x-g))
    const float C = fabsf(inv_den_p[0]) * 2.8853900817779268f;

    int j = blockIdx.x * blockDim.x + threadIdx.x;
    const int stride = gridDim.x * blockDim.x;   // even by construction

    // Grid half is thread-invariant (stride is even): hoist the select.
    const v4f g = ((const v4f*)grid)[j & 1];

    // u_k = exp2(clamp(C*(g.x - xi))) * p_k, p_k = exp2(C*(g_k - g.x)):
    // uniform per-thread constants (3 setup exp2s, then pure muls in loop).
    const float cgx = C * g.x;
    const float p1 = __builtin_amdgcn_exp2f(C * (g.y - g.x));
    const float p2 = __builtin_amdgcn_exp2f(C * (g.z - g.x));
    const float p3 = __builtin_amdgcn_exp2f(C * (g.w - g.x));
    const float q1 = 4.0f * p1, q2 = 4.0f * p2, q3 = 4.0f * p3;

    auto body = [&](float xi, int idx) {
        float e0 = fmaf(-C, xi, cgx);                  // -C*(xi - g.x)
        e0 = fminf(fmaxf(e0, -100.0f), 100.0f);        // v_med3: no inf/NaN
        float u0 = __builtin_amdgcn_exp2f(e0);
        float u1 = u0 * p1, u2 = u0 * p2, u3 = u0 * p3;
        float t0 = 1.0f + u0, t1 = 1.0f + u1, t2 = 1.0f + u2, t3 = 1.0f + u3;
        v4f r;
        r.x = (4.0f * u0) * __builtin_amdgcn_rcpf(t0 * t0);
        r.y = (u0 * q1)   * __builtin_amdgcn_rcpf(t1 * t1);
        r.z = (u0 * q2)   * __builtin_amdgcn_rcpf(t2 * t2);
        r.w = (u0 * q3)   * __builtin_amdgcn_rcpf(t3 * t3);
        __builtin_nontemporal_store(r, &out[idx]);
    };

    // Main loop: 4x unrolled, 4 independent loads in flight.
    const int nfull = n4 - 3 * stride;
    for (; j < nfull; j += 4 * stride) {
        const int ja = j, jb = j + stride, jc = j + 2 * stride, jd = j + 3 * stride;
        float xa = __builtin_nontemporal_load(&x[ja >> 1]);
        float xb = __builtin_nontemporal_load(&x[jb >> 1]);
        float xc = __builtin_nontemporal_load(&x[jc >> 1]);
        float xd = __builtin_nontemporal_load(&x[jd >> 1]);
        body(xa, ja);
        body(xb, jb);
        body(xc, jc);
        body(xd, jd);
    }
    // Tail (not taken for the bench shape: n4 = 64 * stride exactly).
    for (; j < n4; j += stride) {
        body(__builtin_nontemporal_load(&x[j >> 1]), j);
    }
}

extern "C" void kernel_launch(void* const* d_in, const int* in_sizes, int n_in,
                              void* d_out, int out_size, void* d_ws, size_t ws_size,
                              hipStream_t stream) {
    const float* x       = (const float*)d_in[0];   // 16*64*128*128 fp32
    const float* grid    = (const float*)d_in[1];   // 8 fp32
    const float* inv_den = (const float*)d_in[2];   // 1 fp32
    float* out = (float*)d_out;

    const int n4 = out_size / 4;                    // float4 outputs
    const int block = 256;
    int nblocks = (n4 + block - 1) / block;
    if (nblocks > 2048) nblocks = 2048;             // grid-stride the rest
    rswaf_kernel<<<nblocks, block, 0, stream>>>(x, grid, inv_den,
                                                (v4f*)out, n4);
}